// Round 11
// baseline (148.753 us; speedup 1.0000x reference)
//
#include <hip/hip_runtime.h>
#include <hip/hip_fp16.h>
#include <math.h>

#define TWO_PI 6.28318530717958647692f

__device__ __forceinline__ void cmac(float2& a, const float2 b, const float2 c) {
  a.x = fmaf(b.x, c.x, fmaf(-b.y, c.y, a.x));
  a.y = fmaf(b.x, c.y, fmaf(b.y, c.x, a.y));
}
__device__ __forceinline__ __half2 pkh(const float xx, const float yy) {
  return __floats2half2_rn(xx, yy);
}
__device__ __forceinline__ float2 uph(const __half2 h) { return __half22float2(h); }

// cos/sin(2*pi*k/16), k=0..15 (positive exponent convention)
#define W16_C {1.f, 0.92387953f, 0.70710678f, 0.38268343f, 0.f, -0.38268343f, -0.70710678f, -0.92387953f, -1.f, -0.92387953f, -0.70710678f, -0.38268343f, 0.f, 0.38268343f, 0.70710678f, 0.92387953f}
#define W16_S {0.f, 0.38268343f, 0.70710678f, 0.92387953f, 1.f, 0.92387953f, 0.70710678f, 0.38268343f, 0.f, -0.38268343f, -0.70710678f, -0.92387953f, -1.f, -0.92387953f, -0.70710678f, -0.38268343f}

// 16-point +exponent DFT bins X[p1+4*p2], p2=0..3, from 16 classes a[c].
__device__ __forceinline__ void idft16_p1(const float2* a, const int p1,
                                          float2* X) {
  const float WC[16] = W16_C;
  const float WS[16] = W16_S;
  float2 tt[4];
#pragma unroll
  for (int r1 = 0; r1 < 4; ++r1) {
    const float2 q0 = a[r1], q1 = a[r1 + 4], q2 = a[r1 + 8], q3 = a[r1 + 12];
    const float2 s = make_float2(q0.x + q2.x, q0.y + q2.y);
    const float2 d = make_float2(q0.x - q2.x, q0.y - q2.y);
    const float2 u = make_float2(q1.x + q3.x, q1.y + q3.y);
    const float2 e = make_float2(q1.x - q3.x, q1.y - q3.y);
    float2 in;
    if (p1 == 0)      in = make_float2(s.x + u.x, s.y + u.y);
    else if (p1 == 1) in = make_float2(d.x - e.y, d.y + e.x);
    else if (p1 == 2) in = make_float2(s.x - u.x, s.y - u.y);
    else              in = make_float2(d.x + e.y, d.y - e.x);
    const float wc = WC[(r1 * p1) & 15], ws = WS[(r1 * p1) & 15];
    tt[r1] = make_float2(fmaf(in.x, wc, -in.y * ws), fmaf(in.y, wc, in.x * ws));
  }
  const float2 s = make_float2(tt[0].x + tt[2].x, tt[0].y + tt[2].y);
  const float2 d = make_float2(tt[0].x - tt[2].x, tt[0].y - tt[2].y);
  const float2 u = make_float2(tt[1].x + tt[3].x, tt[1].y + tt[3].y);
  const float2 e = make_float2(tt[1].x - tt[3].x, tt[1].y - tt[3].y);
  X[0] = make_float2(s.x + u.x, s.y + u.y);
  X[1] = make_float2(d.x - e.y, d.y + e.x);
  X[2] = make_float2(s.x - u.x, s.y - u.y);
  X[3] = make_float2(d.x + e.y, d.y - e.x);
}

// ---------------------------------------------------------------------------
// F1 (v6): pruned DFT along H, mod-16 classes, fp16 LDS tile + fp16 G out.
// w-tile 16, both duals per thread (shared twiddle), LDS repack epilogue for
// coalesced 64B G writes.  grid 2048 = 128 img * 16 w-tiles, block 256.
// ---------------------------------------------------------------------------
__global__ __launch_bounds__(256) void f1_dft_h(const float* __restrict__ x,
                                                __half2* __restrict__ G) {
  __shared__ float2 twn[256];           // e^{-2pi i t/256}
  __shared__ __half2 yf[64][4][20][2];  // [n1][r][wl(pad16->20)][dual]  40KB
  __shared__ __half2 dl[2][64][16];     // [dual][kx][w] repack buffer     8KB
  const int t = threadIdx.x;
  {
    float sv, cv;
    sincosf(-TWO_PI * (float)t * (1.0f / 256.0f), &sv, &cv);
    twn[t] = make_float2(cv, sv);
  }
  const int bid = blockIdx.x;
  const int img = bid >> 4;            // b*32+c
  const int w0  = (bid & 15) << 4;     // 16-column tile
  const float4* __restrict__ xb = (const float4*)x + (size_t)img * 65536 + w0;
  {
    const int wl  = t & 15;
    const int n1g = t >> 4;            // [0,16)
#pragma unroll
    for (int ii = 0; ii < 4; ++ii) {
      const int n1 = n1g + (ii << 4);
      const float4 v0 = xb[(size_t)(n1)*256 + wl];
      const float4 v1 = xb[(size_t)(n1 + 64) * 256 + wl];
      const float4 v2 = xb[(size_t)(n1 + 128) * 256 + wl];
      const float4 v3 = xb[(size_t)(n1 + 192) * 256 + wl];
      {  // dual 0: (comp0, comp3)
        const float sx = v0.x + v2.x, sy = v0.w + v2.w;
        const float dx = v0.x - v2.x, dy = v0.w - v2.w;
        const float ux = v1.x + v3.x, uy = v1.w + v3.w;
        const float ex = v1.x - v3.x, ey = v1.w - v3.w;
        yf[n1][0][wl][0] = pkh(sx + ux, sy + uy);
        yf[n1][2][wl][0] = pkh(sx - ux, sy - uy);
        yf[n1][1][wl][0] = pkh(dx + ey, dy - ex);
        yf[n1][3][wl][0] = pkh(dx - ey, dy + ex);
      }
      {  // dual 1: (comp1, comp2)
        const float sx = v0.y + v2.y, sy = v0.z + v2.z;
        const float dx = v0.y - v2.y, dy = v0.z - v2.z;
        const float ux = v1.y + v3.y, uy = v1.z + v3.z;
        const float ex = v1.y - v3.y, ey = v1.z - v3.z;
        yf[n1][0][wl][1] = pkh(sx + ux, sy + uy);
        yf[n1][2][wl][1] = pkh(sx - ux, sy - uy);
        yf[n1][1][wl][1] = pkh(dx + ey, dy - ex);
        yf[n1][3][wl][1] = pkh(dx - ey, dy + ex);
      }
    }
  }
  __syncthreads();
  const int wl = t & 15;
  const int kb = t >> 4;               // [0,16)
  const int r  = kb & 3;
  float2 a0[16], a1[16];
#pragma unroll
  for (int c = 0; c < 16; ++c) {
    a0[c] = make_float2(0.f, 0.f);
    a1[c] = make_float2(0.f, 0.f);
  }
  int idx = 0;                         // (n1*kb) & 255
#pragma unroll
  for (int n1 = 0; n1 < 64; ++n1) {
    const float2 tv = twn[idx];
    const float2 hv = *reinterpret_cast<const float2*>(&yf[n1][r][wl][0]);
    const float2 y0 = uph(__builtin_bit_cast(__half2, hv.x));
    const float2 y1 = uph(__builtin_bit_cast(__half2, hv.y));
    cmac(a0[n1 & 15], y0, tv);
    cmac(a1[n1 & 15], y1, tv);
    idx = (idx + kb) & 255;
  }
  const float WC[16] = W16_C;
  const float WS[16] = W16_S;
  float2 D0 = make_float2(0.f, 0.f), D1 = D0, D2 = D0, D3 = D0;
  float2 E0 = D0, E1 = D0, E2 = D0, E3 = D0;
#pragma unroll
  for (int c = 0; c < 16; ++c) {
    const float cc = WC[c], ss = WS[c];
    const float cc2 = WC[(2 * c) & 15], ss2 = WS[(2 * c) & 15];
    {
      const float2 a = a0[c];
      D0.x += a.x;                         D0.y += a.y;
      D1.x = fmaf(a.x, cc,  fmaf( a.y, ss,  D1.x));
      D1.y = fmaf(a.y, cc,  fmaf(-a.x, ss,  D1.y));
      D2.x = fmaf(a.x, cc2, fmaf(-a.y, ss2, D2.x));
      D2.y = fmaf(a.y, cc2, fmaf( a.x, ss2, D2.y));
      D3.x = fmaf(a.x, cc,  fmaf(-a.y, ss,  D3.x));
      D3.y = fmaf(a.y, cc,  fmaf( a.x, ss,  D3.y));
    }
    {
      const float2 a = a1[c];
      E0.x += a.x;                         E0.y += a.y;
      E1.x = fmaf(a.x, cc,  fmaf( a.y, ss,  E1.x));
      E1.y = fmaf(a.y, cc,  fmaf(-a.x, ss,  E1.y));
      E2.x = fmaf(a.x, cc2, fmaf(-a.y, ss2, E2.x));
      E2.y = fmaf(a.y, cc2, fmaf( a.x, ss2, E2.y));
      E3.x = fmaf(a.x, cc,  fmaf(-a.y, ss,  E3.x));
      E3.y = fmaf(a.y, cc,  fmaf( a.x, ss,  E3.y));
    }
  }
  dl[0][kb][wl]      = pkh(D0.x, D0.y);
  dl[0][kb + 16][wl] = pkh(D1.x, D1.y);
  dl[0][kb + 32][wl] = pkh(D2.x, D2.y);
  dl[0][kb + 48][wl] = pkh(D3.x, D3.y);
  dl[1][kb][wl]      = pkh(E0.x, E0.y);
  dl[1][kb + 16][wl] = pkh(E1.x, E1.y);
  dl[1][kb + 32][wl] = pkh(E2.x, E2.y);
  dl[1][kb + 48][wl] = pkh(E3.x, E3.y);
  __syncthreads();
  const __half2* __restrict__ dfl = &dl[0][0][0];
#pragma unroll
  for (int i = 0; i < 8; ++i) {
    const int flat = t + (i << 8);
    const int dual = flat >> 10, kx = (flat >> 4) & 63, w = flat & 15;
    const size_t row = (size_t)(img * 2 + dual) * 64 + kx;
    G[row * 256 + w0 + w] = dfl[flat];
  }
}

// ---------------------------------------------------------------------------
// F2 (v6): pruned DFT along W, mod-16 classes; fp16 G in, fp16 mi out.
// grid 1024 (16 rows/block), block 256 = 16 kslot x 16 trow.
// ---------------------------------------------------------------------------
__global__ __launch_bounds__(256) void f2_dft_w(const __half2* __restrict__ G,
                                                __half2* __restrict__ mi) {
  __shared__ float2 twn[256];
  __shared__ float2 yf[16][65][4];
  const int t = threadIdx.x;
  {
    float sv, cv;
    sincosf(-TWO_PI * (float)t * (1.0f / 256.0f), &sv, &cv);
    twn[t] = make_float2(cv, sv);
  }
  const int row0 = blockIdx.x * 16;
  for (int idx = t; idx < 1024; idx += 256) {
    const int tr = idx >> 6, n1 = idx & 63;
    const __half2* __restrict__ Gp = G + (size_t)(row0 + tr) * 256;
    const float2 z0 = uph(Gp[n1]), z1 = uph(Gp[n1 + 64]);
    const float2 z2 = uph(Gp[n1 + 128]), z3 = uph(Gp[n1 + 192]);
    const float sx = z0.x + z2.x, sy = z0.y + z2.y;
    const float dx = z0.x - z2.x, dy = z0.y - z2.y;
    const float ux = z1.x + z3.x, uy = z1.y + z3.y;
    const float ex = z1.x - z3.x, ey = z1.y - z3.y;
    yf[tr][n1][0] = make_float2(sx + ux, sy + uy);
    yf[tr][n1][2] = make_float2(sx - ux, sy - uy);
    yf[tr][n1][1] = make_float2(dx + ey, dy - ex);
    yf[tr][n1][3] = make_float2(dx - ey, dy + ex);
  }
  __syncthreads();
  const int kslot = t & 15;
  const int trow  = t >> 4;
  const int r     = kslot & 3;
  float2 acc[16];
#pragma unroll
  for (int c = 0; c < 16; ++c) acc[c] = make_float2(0.f, 0.f);
  int idx = 0;
#pragma unroll
  for (int n1 = 0; n1 < 64; ++n1) {
    const float2 tv = twn[idx];
    const float2 yv = yf[trow][n1][r];
    cmac(acc[n1 & 15], yv, tv);
    idx = (idx + kslot) & 255;
  }
  const float WC[16] = W16_C;
  const float WS[16] = W16_S;
  float2 D[4];
  D[0] = make_float2(0.f, 0.f); D[1] = D[0]; D[2] = D[0]; D[3] = D[0];
#pragma unroll
  for (int c = 0; c < 16; ++c) {
    const float2 a = acc[c];
    const float cc = WC[c], ss = WS[c];
    const float cc2 = WC[(2 * c) & 15], ss2 = WS[(2 * c) & 15];
    D[0].x += a.x;                        D[0].y += a.y;
    D[1].x = fmaf(a.x, cc,  fmaf( a.y, ss,  D[1].x));
    D[1].y = fmaf(a.y, cc,  fmaf(-a.x, ss,  D[1].y));
    D[2].x = fmaf(a.x, cc2, fmaf(-a.y, ss2, D[2].x));
    D[2].y = fmaf(a.y, cc2, fmaf( a.x, ss2, D[2].y));
    D[3].x = fmaf(a.x, cc,  fmaf(-a.y, ss,  D[3].x));
    D[3].y = fmaf(a.y, cc,  fmaf( a.x, ss,  D[3].y));
  }
  const int row  = row0 + trow;       // ((img*2+dual)*64 + kx)
  const int kx   = row & 63;
  const int dual = (row >> 6) & 1;
  const int bc   = row >> 7;
  const int b = bc >> 5, cc = bc & 31;
#pragma unroll
  for (int m = 0; m < 4; ++m) {
    const int kyi = kslot + (m << 4);
    mi[((size_t)((b * 2 + dual) * 32 + cc)) * 4096 + kx * 64 + kyi] =
        pkh(D[m].x, D[m].y);
  }
}

// ---------------------------------------------------------------------------
// EIN (v10): v6 structure at 2x occupancy. 8-mode tiles, block 512 =
// 8q x 16o x 4ch (c-split 8 each), si 16KB + red 17.4KB -> 4 blocks/CU
// (32 waves/CU). Weights read once, scalar loads, 2-deep even/odd prefetch,
// 2-stage LDS reduce.  grid 1024 = 512 mode-tiles(8) * 2 o-halves.
// ---------------------------------------------------------------------------
__global__ __launch_bounds__(512) void ein_k(const __half2* __restrict__ mi,
                                             const float* __restrict__ wgt,
                                             __half2* __restrict__ mo) {
  __shared__ float si[4][128][8];    // [b][s*32+c][q]  16KB
  __shared__ float red[2][128][17];  // [grp][oq][b*4+r pad17]  17.4KB
  const int t = threadIdx.x;
  const int bid = blockIdx.x;
  const int m0 = (bid >> 1) << 3;    // 8-mode tile
  const int oh = bid & 1;
  for (int idx = t; idx < 2048; idx += 512) {
    const int q = idx & 7, c = (idx >> 3) & 31, dual = (idx >> 8) & 1, b = idx >> 9;
    const float2 f = uph(mi[((size_t)((b * 2 + dual) * 32 + c)) * 4096 + m0 + q]);
    if (dual == 0) { si[b][c][q] = f.x;      si[b][96 + c][q] = f.y; }
    else           { si[b][32 + c][q] = f.x; si[b][64 + c][q] = f.y; }
  }
  __syncthreads();
  const int q   = t & 7;
  const int o16 = (t >> 3) & 15;
  const int ch  = t >> 7;            // [0,4), 8 c each
  const int o   = oh * 16 + o16;
  const int c0  = ch << 3;
  const int oq  = o16 * 8 + q;       // [0,128)
  const float* __restrict__ wb = wgt + (size_t)o * 131072 + m0 + q;
  float acc[4][4];
#pragma unroll
  for (int b = 0; b < 4; ++b)
#pragma unroll
    for (int r = 0; r < 4; ++r) acc[b][r] = 0.f;
  float wE[4], wO[4];
#pragma unroll
  for (int j = 0; j < 4; ++j)
    wE[j] = wb[(size_t)j * 4194304 + (size_t)c0 * 4096];
#pragma unroll
  for (int j = 0; j < 4; ++j)
    wO[j] = wb[(size_t)j * 4194304 + (size_t)(c0 + 1) * 4096];
#pragma unroll 1
  for (int cc = 0; cc < 8; cc += 2) {
    const int c = c0 + cc;
    {  // even c, uses wE, refill for c+2
      const float iv0 = si[0][c][q], jv0 = si[1][c][q], kv0 = si[2][c][q], lv0 = si[3][c][q];
      const float iv1 = si[0][32 + c][q], jv1 = si[1][32 + c][q], kv1 = si[2][32 + c][q], lv1 = si[3][32 + c][q];
      const float iv2 = si[0][64 + c][q], jv2 = si[1][64 + c][q], kv2 = si[2][64 + c][q], lv2 = si[3][64 + c][q];
      const float iv3 = si[0][96 + c][q], jv3 = si[1][96 + c][q], kv3 = si[2][96 + c][q], lv3 = si[3][96 + c][q];
      acc[0][0] += wE[0] * iv0 + wE[1] * iv1 + wE[2] * iv2 - wE[3] * iv3;
      acc[0][1] += wE[1] * iv0 + wE[0] * iv1 - wE[3] * iv2 + wE[2] * iv3;
      acc[0][2] += wE[2] * iv0 + wE[3] * iv1 + wE[0] * iv2 - wE[1] * iv3;
      acc[0][3] += wE[3] * iv0 + wE[2] * iv1 - wE[1] * iv2 + wE[0] * iv3;
      acc[1][0] += wE[0] * jv0 + wE[1] * jv1 + wE[2] * jv2 - wE[3] * jv3;
      acc[1][1] += wE[1] * jv0 + wE[0] * jv1 - wE[3] * jv2 + wE[2] * jv3;
      acc[1][2] += wE[2] * jv0 + wE[3] * jv1 + wE[0] * jv2 - wE[1] * jv3;
      acc[1][3] += wE[3] * jv0 + wE[2] * jv1 - wE[1] * jv2 + wE[0] * jv3;
      acc[2][0] += wE[0] * kv0 + wE[1] * kv1 + wE[2] * kv2 - wE[3] * kv3;
      acc[2][1] += wE[1] * kv0 + wE[0] * kv1 - wE[3] * kv2 + wE[2] * kv3;
      acc[2][2] += wE[2] * kv0 + wE[3] * kv1 + wE[0] * kv2 - wE[1] * kv3;
      acc[2][3] += wE[3] * kv0 + wE[2] * kv1 - wE[1] * kv2 + wE[0] * kv3;
      acc[3][0] += wE[0] * lv0 + wE[1] * lv1 + wE[2] * lv2 - wE[3] * lv3;
      acc[3][1] += wE[1] * lv0 + wE[0] * lv1 - wE[3] * lv2 + wE[2] * lv3;
      acc[3][2] += wE[2] * lv0 + wE[3] * lv1 + wE[0] * lv2 - wE[1] * lv3;
      acc[3][3] += wE[3] * lv0 + wE[2] * lv1 - wE[1] * lv2 + wE[0] * lv3;
      if (cc + 2 < 8) {
#pragma unroll
        for (int j = 0; j < 4; ++j)
          wE[j] = wb[(size_t)j * 4194304 + (size_t)(c + 2) * 4096];
      }
    }
    {  // odd c, uses wO, refill for c+3
      const int c1 = c + 1;
      const float iv0 = si[0][c1][q], jv0 = si[1][c1][q], kv0 = si[2][c1][q], lv0 = si[3][c1][q];
      const float iv1 = si[0][32 + c1][q], jv1 = si[1][32 + c1][q], kv1 = si[2][32 + c1][q], lv1 = si[3][32 + c1][q];
      const float iv2 = si[0][64 + c1][q], jv2 = si[1][64 + c1][q], kv2 = si[2][64 + c1][q], lv2 = si[3][64 + c1][q];
      const float iv3 = si[0][96 + c1][q], jv3 = si[1][96 + c1][q], kv3 = si[2][96 + c1][q], lv3 = si[3][96 + c1][q];
      acc[0][0] += wO[0] * iv0 + wO[1] * iv1 + wO[2] * iv2 - wO[3] * iv3;
      acc[0][1] += wO[1] * iv0 + wO[0] * iv1 - wO[3] * iv2 + wO[2] * iv3;
      acc[0][2] += wO[2] * iv0 + wO[3] * iv1 + wO[0] * iv2 - wO[1] * iv3;
      acc[0][3] += wO[3] * iv0 + wO[2] * iv1 - wO[1] * iv2 + wO[0] * iv3;
      acc[1][0] += wO[0] * jv0 + wO[1] * jv1 + wO[2] * jv2 - wO[3] * jv3;
      acc[1][1] += wO[1] * jv0 + wO[0] * jv1 - wO[3] * jv2 + wO[2] * jv3;
      acc[1][2] += wO[2] * jv0 + wO[3] * jv1 + wO[0] * jv2 - wO[1] * jv3;
      acc[1][3] += wO[3] * jv0 + wO[2] * jv1 - wO[1] * jv2 + wO[0] * jv3;
      acc[2][0] += wO[0] * kv0 + wO[1] * kv1 + wO[2] * kv2 - wO[3] * kv3;
      acc[2][1] += wO[1] * kv0 + wO[0] * kv1 - wO[3] * kv2 + wO[2] * kv3;
      acc[2][2] += wO[2] * kv0 + wO[3] * kv1 + wO[0] * kv2 - wO[1] * kv3;
      acc[2][3] += wO[3] * kv0 + wO[2] * kv1 - wO[1] * kv2 + wO[0] * kv3;
      acc[3][0] += wO[0] * lv0 + wO[1] * lv1 + wO[2] * lv2 - wO[3] * lv3;
      acc[3][1] += wO[1] * lv0 + wO[0] * lv1 - wO[3] * lv2 + wO[2] * lv3;
      acc[3][2] += wO[2] * lv0 + wO[3] * lv1 + wO[0] * lv2 - wO[1] * lv3;
      acc[3][3] += wO[3] * lv0 + wO[2] * lv1 - wO[1] * lv2 + wO[0] * lv3;
      if (cc + 3 < 8) {
#pragma unroll
        for (int j = 0; j < 4; ++j)
          wO[j] = wb[(size_t)j * 4194304 + (size_t)(c + 3) * 4096];
      }
    }
  }
  // ---- reduce over ch: stage 1 (ch2->grp0, ch3->grp1; ch0+=grp0, ch1+=grp1)
  __syncthreads();
  if (ch >= 2) {
    float* rp = &red[ch - 2][oq][0];
#pragma unroll
    for (int b = 0; b < 4; ++b)
#pragma unroll
      for (int r = 0; r < 4; ++r) rp[b * 4 + r] = acc[b][r];
  }
  __syncthreads();
  if (ch < 2) {
    const float* rp = &red[ch][oq][0];
#pragma unroll
    for (int b = 0; b < 4; ++b)
#pragma unroll
      for (int r = 0; r < 4; ++r) acc[b][r] += rp[b * 4 + r];
  }
  __syncthreads();
  if (ch == 1) {
    float* rp = &red[0][oq][0];
#pragma unroll
    for (int b = 0; b < 4; ++b)
#pragma unroll
      for (int r = 0; r < 4; ++r) rp[b * 4 + r] = acc[b][r];
  }
  __syncthreads();
  if (ch == 0) {
    const float* rp = &red[0][oq][0];
#pragma unroll
    for (int b = 0; b < 4; ++b)
#pragma unroll
      for (int r = 0; r < 4; ++r) acc[b][r] += rp[b * 4 + r];
#pragma unroll
    for (int b = 0; b < 4; ++b) {
      mo[((size_t)((b * 2 + 0) * 32 + o)) * 4096 + m0 + q] = pkh(acc[b][0], acc[b][3]);
      mo[((size_t)((b * 2 + 1) * 32 + o)) * 4096 + m0 + q] = pkh(acc[b][1], acc[b][2]);
    }
  }
}

// ---------------------------------------------------------------------------
// I1 (v6): inverse DFT along W, mod-16 classes + idft16; fp16 mo in, fp16 T out.
// grid 1024 (16 rows/block), block 256 = 16 n1 x 16 trow.
// ---------------------------------------------------------------------------
__global__ __launch_bounds__(256) void i1_idft_w(const __half2* __restrict__ mo,
                                                 __half2* __restrict__ T) {
  __shared__ float2 twc[256];       // e^{+2pi i t/256}
  __shared__ float2 srow[16][66];
  const int t = threadIdx.x;
  {
    float sv, cv;
    sincosf(TWO_PI * (float)t * (1.0f / 256.0f), &sv, &cv);
    twc[t] = make_float2(cv, sv);
  }
  const int row0 = blockIdx.x * 16;
  for (int idx = t; idx < 1024; idx += 256) {
    const int tr = idx >> 6, ky = idx & 63;
    const int row = row0 + tr;        // ((bo*2+dual)*64 + kx)
    const int kx = row & 63;
    const int dual = (row >> 6) & 1;
    const int bo = row >> 7;
    const int b = bo >> 5, o = bo & 31;
    srow[tr][ky] =
        uph(mo[((size_t)((b * 2 + dual) * 32 + o)) * 4096 + kx * 64 + ky]);
  }
  __syncthreads();
  const int n1   = t & 15;
  const int trow = t >> 4;
  float2 a[16];
#pragma unroll
  for (int c = 0; c < 16; ++c) a[c] = make_float2(0.f, 0.f);
  int idx = 0;                       // (kyf*n1) & 255
#pragma unroll
  for (int kyi = 0; kyi < 64; ++kyi) {
    if (kyi == 32) idx = (idx + 192 * n1) & 255;
    cmac(a[kyi & 15], srow[trow][kyi], twc[idx]);
    idx = (idx + n1) & 255;
  }
  const int row = row0 + trow;
  __half2* __restrict__ Tp = T + (size_t)row * 256;
#pragma unroll
  for (int p1 = 0; p1 < 4; ++p1) {
    float2 X[4];
    idft16_p1(a, p1, X);
#pragma unroll
    for (int p2 = 0; p2 < 4; ++p2)
      Tp[n1 + 16 * (p1 + 4 * p2)] = pkh(X[p2].x, X[p2].y);
  }
}

// ---------------------------------------------------------------------------
// I2 (v6): inverse DFT along H, mod-16 classes + idft16; fp16 T in, fp32 out.
// grid 2048 = 128 images * 16 w-tiles(16), block 256.
// ---------------------------------------------------------------------------
__global__ __launch_bounds__(256) void i2_idft_h(const __half2* __restrict__ T,
                                                 float* __restrict__ out) {
  __shared__ float2 twc[256];       // e^{+2pi i t/256}
  __shared__ float2 Tl[2][64][16];
  const int t = threadIdx.x;
  {
    float sv, cv;
    sincosf(TWO_PI * (float)t * (1.0f / 256.0f), &sv, &cv);
    twc[t] = make_float2(cv, sv);
  }
  const int bid = blockIdx.x;
  const int bo = bid >> 4;
  const int w0 = (bid & 15) << 4;
  const __half2* __restrict__ Tp = T + (size_t)bo * 32768;
  for (int idx = t; idx < 2048; idx += 256) {
    const int ww = idx & 15, kxi = (idx >> 4) & 63, dual = idx >> 10;
    Tl[dual][kxi][ww] = uph(Tp[((size_t)dual * 64 + kxi) * 256 + w0 + ww]);
  }
  __syncthreads();
  const int wl = t & 15;
  const int n1 = t >> 4;
  float2 a0[16], a1[16];
#pragma unroll
  for (int c = 0; c < 16; ++c) {
    a0[c] = make_float2(0.f, 0.f);
    a1[c] = make_float2(0.f, 0.f);
  }
  int idx = 0;
#pragma unroll
  for (int kxi = 0; kxi < 64; ++kxi) {
    if (kxi == 32) idx = (idx + 192 * n1) & 255;
    const float2 tv = twc[idx];
    cmac(a0[kxi & 15], Tl[0][kxi][wl], tv);
    cmac(a1[kxi & 15], Tl[1][kxi][wl], tv);
    idx = (idx + n1) & 255;
  }
  const float sc = 1.0f / 65536.0f;
  float4* __restrict__ op = (float4*)out + (size_t)bo * 65536 + w0 + wl;
#pragma unroll
  for (int p1 = 0; p1 < 4; ++p1) {
    float2 X0[4], X1[4];
    idft16_p1(a0, p1, X0);
    idft16_p1(a1, p1, X1);
#pragma unroll
    for (int p2 = 0; p2 < 4; ++p2) {
      const int h = n1 + 16 * (p1 + 4 * p2);
      op[(size_t)h * 256] = make_float4(X0[p2].x * sc, X1[p2].x * sc,
                                        X1[p2].y * sc, X0[p2].y * sc);
    }
  }
}

extern "C" void kernel_launch(void* const* d_in, const int* in_sizes, int n_in,
                              void* d_out, int out_size, void* d_ws, size_t ws_size,
                              hipStream_t stream) {
  const float* x = (const float*)d_in[0];
  const float* wgt = (const float*)d_in[1];
  float* out = (float*)d_out;
  __half2* G  = (__half2*)d_ws;     // 4,194,304 half2 (16.8 MB), reused as T
  __half2* mi = G + 4194304;        // 1,048,576 half2
  __half2* mo = mi + 1048576;       // 1,048,576 half2

  hipLaunchKernelGGL(f1_dft_h, dim3(2048), dim3(256), 0, stream, x, G);
  hipLaunchKernelGGL(f2_dft_w, dim3(1024), dim3(256), 0, stream, G, mi);
  hipLaunchKernelGGL(ein_k,    dim3(1024), dim3(512), 0, stream, mi, wgt, mo);
  hipLaunchKernelGGL(i1_idft_w, dim3(1024), dim3(256), 0, stream, mo, G);
  hipLaunchKernelGGL(i2_idft_h, dim3(2048), dim3(256), 0, stream, G, out);
}

// Round 12
// 126.394 us; speedup vs baseline: 1.1769x; 1.1769x over previous
//
#include <hip/hip_runtime.h>
#include <hip/hip_fp16.h>
#include <math.h>

#define TWO_PI 6.28318530717958647692f

__device__ __forceinline__ void cmac(float2& a, const float2 b, const float2 c) {
  a.x = fmaf(b.x, c.x, fmaf(-b.y, c.y, a.x));
  a.y = fmaf(b.x, c.y, fmaf(b.y, c.x, a.y));
}
__device__ __forceinline__ __half2 pkh(const float xx, const float yy) {
  return __floats2half2_rn(xx, yy);
}
__device__ __forceinline__ float2 uph(const __half2 h) { return __half22float2(h); }

// cos/sin(2*pi*k/16), k=0..15 (positive exponent convention)
#define W16_C {1.f, 0.92387953f, 0.70710678f, 0.38268343f, 0.f, -0.38268343f, -0.70710678f, -0.92387953f, -1.f, -0.92387953f, -0.70710678f, -0.38268343f, 0.f, 0.38268343f, 0.70710678f, 0.92387953f}
#define W16_S {0.f, 0.38268343f, 0.70710678f, 0.92387953f, 1.f, 0.92387953f, 0.70710678f, 0.38268343f, 0.f, -0.38268343f, -0.70710678f, -0.92387953f, -1.f, -0.92387953f, -0.70710678f, -0.38268343f}

// 16-point +exponent DFT bins X[p1+4*p2], p2=0..3, from 16 classes a[c].
__device__ __forceinline__ void idft16_p1(const float2* a, const int p1,
                                          float2* X) {
  const float WC[16] = W16_C;
  const float WS[16] = W16_S;
  float2 tt[4];
#pragma unroll
  for (int r1 = 0; r1 < 4; ++r1) {
    const float2 q0 = a[r1], q1 = a[r1 + 4], q2 = a[r1 + 8], q3 = a[r1 + 12];
    const float2 s = make_float2(q0.x + q2.x, q0.y + q2.y);
    const float2 d = make_float2(q0.x - q2.x, q0.y - q2.y);
    const float2 u = make_float2(q1.x + q3.x, q1.y + q3.y);
    const float2 e = make_float2(q1.x - q3.x, q1.y - q3.y);
    float2 in;
    if (p1 == 0)      in = make_float2(s.x + u.x, s.y + u.y);
    else if (p1 == 1) in = make_float2(d.x - e.y, d.y + e.x);
    else if (p1 == 2) in = make_float2(s.x - u.x, s.y - u.y);
    else              in = make_float2(d.x + e.y, d.y - e.x);
    const float wc = WC[(r1 * p1) & 15], ws = WS[(r1 * p1) & 15];
    tt[r1] = make_float2(fmaf(in.x, wc, -in.y * ws), fmaf(in.y, wc, in.x * ws));
  }
  const float2 s = make_float2(tt[0].x + tt[2].x, tt[0].y + tt[2].y);
  const float2 d = make_float2(tt[0].x - tt[2].x, tt[0].y - tt[2].y);
  const float2 u = make_float2(tt[1].x + tt[3].x, tt[1].y + tt[3].y);
  const float2 e = make_float2(tt[1].x - tt[3].x, tt[1].y - tt[3].y);
  X[0] = make_float2(s.x + u.x, s.y + u.y);
  X[1] = make_float2(d.x - e.y, d.y + e.x);
  X[2] = make_float2(s.x - u.x, s.y - u.y);
  X[3] = make_float2(d.x + e.y, d.y - e.x);
}

// ---------------------------------------------------------------------------
// F1 (v6): pruned DFT along H, mod-16 classes, fp16 LDS tile + fp16 G out.
// w-tile 16, both duals per thread (shared twiddle), LDS repack epilogue for
// coalesced 64B G writes.  grid 2048 = 128 img * 16 w-tiles, block 256.
// ---------------------------------------------------------------------------
__global__ __launch_bounds__(256) void f1_dft_h(const float* __restrict__ x,
                                                __half2* __restrict__ G) {
  __shared__ float2 twn[256];           // e^{-2pi i t/256}
  __shared__ __half2 yf[64][4][20][2];  // [n1][r][wl(pad16->20)][dual]  40KB
  __shared__ __half2 dl[2][64][16];     // [dual][kx][w] repack buffer     8KB
  const int t = threadIdx.x;
  {
    float sv, cv;
    sincosf(-TWO_PI * (float)t * (1.0f / 256.0f), &sv, &cv);
    twn[t] = make_float2(cv, sv);
  }
  const int bid = blockIdx.x;
  const int img = bid >> 4;            // b*32+c
  const int w0  = (bid & 15) << 4;     // 16-column tile
  const float4* __restrict__ xb = (const float4*)x + (size_t)img * 65536 + w0;
  {
    const int wl  = t & 15;
    const int n1g = t >> 4;            // [0,16)
#pragma unroll
    for (int ii = 0; ii < 4; ++ii) {
      const int n1 = n1g + (ii << 4);
      const float4 v0 = xb[(size_t)(n1)*256 + wl];
      const float4 v1 = xb[(size_t)(n1 + 64) * 256 + wl];
      const float4 v2 = xb[(size_t)(n1 + 128) * 256 + wl];
      const float4 v3 = xb[(size_t)(n1 + 192) * 256 + wl];
      {  // dual 0: (comp0, comp3)
        const float sx = v0.x + v2.x, sy = v0.w + v2.w;
        const float dx = v0.x - v2.x, dy = v0.w - v2.w;
        const float ux = v1.x + v3.x, uy = v1.w + v3.w;
        const float ex = v1.x - v3.x, ey = v1.w - v3.w;
        yf[n1][0][wl][0] = pkh(sx + ux, sy + uy);
        yf[n1][2][wl][0] = pkh(sx - ux, sy - uy);
        yf[n1][1][wl][0] = pkh(dx + ey, dy - ex);
        yf[n1][3][wl][0] = pkh(dx - ey, dy + ex);
      }
      {  // dual 1: (comp1, comp2)
        const float sx = v0.y + v2.y, sy = v0.z + v2.z;
        const float dx = v0.y - v2.y, dy = v0.z - v2.z;
        const float ux = v1.y + v3.y, uy = v1.z + v3.z;
        const float ex = v1.y - v3.y, ey = v1.z - v3.z;
        yf[n1][0][wl][1] = pkh(sx + ux, sy + uy);
        yf[n1][2][wl][1] = pkh(sx - ux, sy - uy);
        yf[n1][1][wl][1] = pkh(dx + ey, dy - ex);
        yf[n1][3][wl][1] = pkh(dx - ey, dy + ex);
      }
    }
  }
  __syncthreads();
  const int wl = t & 15;
  const int kb = t >> 4;               // [0,16)
  const int r  = kb & 3;
  float2 a0[16], a1[16];
#pragma unroll
  for (int c = 0; c < 16; ++c) {
    a0[c] = make_float2(0.f, 0.f);
    a1[c] = make_float2(0.f, 0.f);
  }
  int idx = 0;                         // (n1*kb) & 255
#pragma unroll
  for (int n1 = 0; n1 < 64; ++n1) {
    const float2 tv = twn[idx];
    const float2 hv = *reinterpret_cast<const float2*>(&yf[n1][r][wl][0]);
    const float2 y0 = uph(__builtin_bit_cast(__half2, hv.x));
    const float2 y1 = uph(__builtin_bit_cast(__half2, hv.y));
    cmac(a0[n1 & 15], y0, tv);
    cmac(a1[n1 & 15], y1, tv);
    idx = (idx + kb) & 255;
  }
  const float WC[16] = W16_C;
  const float WS[16] = W16_S;
  float2 D0 = make_float2(0.f, 0.f), D1 = D0, D2 = D0, D3 = D0;
  float2 E0 = D0, E1 = D0, E2 = D0, E3 = D0;
#pragma unroll
  for (int c = 0; c < 16; ++c) {
    const float cc = WC[c], ss = WS[c];
    const float cc2 = WC[(2 * c) & 15], ss2 = WS[(2 * c) & 15];
    {
      const float2 a = a0[c];
      D0.x += a.x;                         D0.y += a.y;
      D1.x = fmaf(a.x, cc,  fmaf( a.y, ss,  D1.x));
      D1.y = fmaf(a.y, cc,  fmaf(-a.x, ss,  D1.y));
      D2.x = fmaf(a.x, cc2, fmaf(-a.y, ss2, D2.x));
      D2.y = fmaf(a.y, cc2, fmaf( a.x, ss2, D2.y));
      D3.x = fmaf(a.x, cc,  fmaf(-a.y, ss,  D3.x));
      D3.y = fmaf(a.y, cc,  fmaf( a.x, ss,  D3.y));
    }
    {
      const float2 a = a1[c];
      E0.x += a.x;                         E0.y += a.y;
      E1.x = fmaf(a.x, cc,  fmaf( a.y, ss,  E1.x));
      E1.y = fmaf(a.y, cc,  fmaf(-a.x, ss,  E1.y));
      E2.x = fmaf(a.x, cc2, fmaf(-a.y, ss2, E2.x));
      E2.y = fmaf(a.y, cc2, fmaf( a.x, ss2, E2.y));
      E3.x = fmaf(a.x, cc,  fmaf(-a.y, ss,  E3.x));
      E3.y = fmaf(a.y, cc,  fmaf( a.x, ss,  E3.y));
    }
  }
  dl[0][kb][wl]      = pkh(D0.x, D0.y);
  dl[0][kb + 16][wl] = pkh(D1.x, D1.y);
  dl[0][kb + 32][wl] = pkh(D2.x, D2.y);
  dl[0][kb + 48][wl] = pkh(D3.x, D3.y);
  dl[1][kb][wl]      = pkh(E0.x, E0.y);
  dl[1][kb + 16][wl] = pkh(E1.x, E1.y);
  dl[1][kb + 32][wl] = pkh(E2.x, E2.y);
  dl[1][kb + 48][wl] = pkh(E3.x, E3.y);
  __syncthreads();
  const __half2* __restrict__ dfl = &dl[0][0][0];
#pragma unroll
  for (int i = 0; i < 8; ++i) {
    const int flat = t + (i << 8);
    const int dual = flat >> 10, kx = (flat >> 4) & 63, w = flat & 15;
    const size_t row = (size_t)(img * 2 + dual) * 64 + kx;
    G[row * 256 + w0 + w] = dfl[flat];
  }
}

// ---------------------------------------------------------------------------
// F2 (v6): pruned DFT along W, mod-16 classes; fp16 G in, fp16 mi out.
// grid 1024 (16 rows/block), block 256 = 16 kslot x 16 trow.
// ---------------------------------------------------------------------------
__global__ __launch_bounds__(256) void f2_dft_w(const __half2* __restrict__ G,
                                                __half2* __restrict__ mi) {
  __shared__ float2 twn[256];
  __shared__ float2 yf[16][65][4];
  const int t = threadIdx.x;
  {
    float sv, cv;
    sincosf(-TWO_PI * (float)t * (1.0f / 256.0f), &sv, &cv);
    twn[t] = make_float2(cv, sv);
  }
  const int row0 = blockIdx.x * 16;
  for (int idx = t; idx < 1024; idx += 256) {
    const int tr = idx >> 6, n1 = idx & 63;
    const __half2* __restrict__ Gp = G + (size_t)(row0 + tr) * 256;
    const float2 z0 = uph(Gp[n1]), z1 = uph(Gp[n1 + 64]);
    const float2 z2 = uph(Gp[n1 + 128]), z3 = uph(Gp[n1 + 192]);
    const float sx = z0.x + z2.x, sy = z0.y + z2.y;
    const float dx = z0.x - z2.x, dy = z0.y - z2.y;
    const float ux = z1.x + z3.x, uy = z1.y + z3.y;
    const float ex = z1.x - z3.x, ey = z1.y - z3.y;
    yf[tr][n1][0] = make_float2(sx + ux, sy + uy);
    yf[tr][n1][2] = make_float2(sx - ux, sy - uy);
    yf[tr][n1][1] = make_float2(dx + ey, dy - ex);
    yf[tr][n1][3] = make_float2(dx - ey, dy + ex);
  }
  __syncthreads();
  const int kslot = t & 15;
  const int trow  = t >> 4;
  const int r     = kslot & 3;
  float2 acc[16];
#pragma unroll
  for (int c = 0; c < 16; ++c) acc[c] = make_float2(0.f, 0.f);
  int idx = 0;
#pragma unroll
  for (int n1 = 0; n1 < 64; ++n1) {
    const float2 tv = twn[idx];
    const float2 yv = yf[trow][n1][r];
    cmac(acc[n1 & 15], yv, tv);
    idx = (idx + kslot) & 255;
  }
  const float WC[16] = W16_C;
  const float WS[16] = W16_S;
  float2 D[4];
  D[0] = make_float2(0.f, 0.f); D[1] = D[0]; D[2] = D[0]; D[3] = D[0];
#pragma unroll
  for (int c = 0; c < 16; ++c) {
    const float2 a = acc[c];
    const float cc = WC[c], ss = WS[c];
    const float cc2 = WC[(2 * c) & 15], ss2 = WS[(2 * c) & 15];
    D[0].x += a.x;                        D[0].y += a.y;
    D[1].x = fmaf(a.x, cc,  fmaf( a.y, ss,  D[1].x));
    D[1].y = fmaf(a.y, cc,  fmaf(-a.x, ss,  D[1].y));
    D[2].x = fmaf(a.x, cc2, fmaf(-a.y, ss2, D[2].x));
    D[2].y = fmaf(a.y, cc2, fmaf( a.x, ss2, D[2].y));
    D[3].x = fmaf(a.x, cc,  fmaf(-a.y, ss,  D[3].x));
    D[3].y = fmaf(a.y, cc,  fmaf( a.x, ss,  D[3].y));
  }
  const int row  = row0 + trow;       // ((img*2+dual)*64 + kx)
  const int kx   = row & 63;
  const int dual = (row >> 6) & 1;
  const int bc   = row >> 7;
  const int b = bc >> 5, cc = bc & 31;
#pragma unroll
  for (int m = 0; m < 4; ++m) {
    const int kyi = kslot + (m << 4);
    mi[((size_t)((b * 2 + dual) * 32 + cc)) * 4096 + kx * 64 + kyi] =
        pkh(D[m].x, D[m].y);
  }
}

// ---------------------------------------------------------------------------
// EIN (v6): Clifford mix; fp16 mi/mo (half2 = (Re,Im) per dual); c-split
// 512-thread blocks (16 waves/CU) + 2-deep weight prefetch; LDS reduce.
// grid 512 = 256 mode-tiles(16) * 2 o-halves.
// ---------------------------------------------------------------------------
__global__ __launch_bounds__(512) void ein_k(const __half2* __restrict__ mi,
                                             const float* __restrict__ wgt,
                                             __half2* __restrict__ mo) {
  __shared__ float si[4][128][16];  // [b][s*32+c][q]  32KB
  const int t = threadIdx.x;
  const int bid = blockIdx.x;
  const int m0 = (bid >> 1) << 4;
  const int oh = bid & 1;
  for (int idx = t; idx < 4096; idx += 512) {
    const int q = idx & 15, c = (idx >> 4) & 31, dual = (idx >> 9) & 1, b = idx >> 10;
    const float2 f = uph(mi[((size_t)((b * 2 + dual) * 32 + c)) * 4096 + m0 + q]);
    if (dual == 0) { si[b][c][q] = f.x;      si[b][96 + c][q] = f.y; }
    else           { si[b][32 + c][q] = f.x; si[b][64 + c][q] = f.y; }
  }
  __syncthreads();
  const int q  = t & 15;
  const int o  = oh * 16 + ((t >> 4) & 15);
  const int ch = t >> 8;             // c-half
  const int c0 = ch << 4;
  const float* __restrict__ wb = wgt + (size_t)o * 131072 + m0 + q;
  float acc[4][4];
#pragma unroll
  for (int b = 0; b < 4; ++b)
#pragma unroll
    for (int r = 0; r < 4; ++r) acc[b][r] = 0.f;
  float wA[4], wB[4];
#pragma unroll
  for (int j = 0; j < 4; ++j) wA[j] = wb[(size_t)j * 4194304 + (size_t)c0 * 4096];
#pragma unroll
  for (int j = 0; j < 4; ++j) wB[j] = wb[(size_t)j * 4194304 + (size_t)(c0 + 1) * 4096];
#pragma unroll 1
  for (int c = c0; c < c0 + 16; ++c) {
    float wv[4];
#pragma unroll
    for (int j = 0; j < 4; ++j) { wv[j] = wA[j]; wA[j] = wB[j]; }
    if (c + 2 < c0 + 16) {
#pragma unroll
      for (int j = 0; j < 4; ++j)
        wB[j] = wb[(size_t)j * 4194304 + (size_t)(c + 2) * 4096];
    }
#pragma unroll
    for (int b = 0; b < 4; ++b) {
      const float iv0 = si[b][c][q];
      const float iv1 = si[b][32 + c][q];
      const float iv2 = si[b][64 + c][q];
      const float iv3 = si[b][96 + c][q];
      acc[b][0] += wv[0] * iv0 + wv[1] * iv1 + wv[2] * iv2 - wv[3] * iv3;
      acc[b][1] += wv[1] * iv0 + wv[0] * iv1 - wv[3] * iv2 + wv[2] * iv3;
      acc[b][2] += wv[2] * iv0 + wv[3] * iv1 + wv[0] * iv2 - wv[1] * iv3;
      acc[b][3] += wv[3] * iv0 + wv[2] * iv1 - wv[1] * iv2 + wv[0] * iv3;
    }
  }
  __syncthreads();                    // si reads done; reuse as reduce buffer
  float* __restrict__ red = &si[0][0][0];   // 256*17 = 4352 floats, fits
  if (ch == 1) {
    const int tt = t & 255;
#pragma unroll
    for (int b = 0; b < 4; ++b)
#pragma unroll
      for (int r = 0; r < 4; ++r) red[tt * 17 + b * 4 + r] = acc[b][r];
  }
  __syncthreads();
  if (ch == 0) {
#pragma unroll
    for (int b = 0; b < 4; ++b)
#pragma unroll
      for (int r = 0; r < 4; ++r) acc[b][r] += red[t * 17 + b * 4 + r];
#pragma unroll
    for (int b = 0; b < 4; ++b) {
      mo[((size_t)((b * 2 + 0) * 32 + o)) * 4096 + m0 + q] = pkh(acc[b][0], acc[b][3]);
      mo[((size_t)((b * 2 + 1) * 32 + o)) * 4096 + m0 + q] = pkh(acc[b][1], acc[b][2]);
    }
  }
}

// ---------------------------------------------------------------------------
// I1 (v6): inverse DFT along W, mod-16 classes + idft16; fp16 mo in, fp16 T out.
// grid 1024 (16 rows/block), block 256 = 16 n1 x 16 trow.
// ---------------------------------------------------------------------------
__global__ __launch_bounds__(256) void i1_idft_w(const __half2* __restrict__ mo,
                                                 __half2* __restrict__ T) {
  __shared__ float2 twc[256];       // e^{+2pi i t/256}
  __shared__ float2 srow[16][66];
  const int t = threadIdx.x;
  {
    float sv, cv;
    sincosf(TWO_PI * (float)t * (1.0f / 256.0f), &sv, &cv);
    twc[t] = make_float2(cv, sv);
  }
  const int row0 = blockIdx.x * 16;
  for (int idx = t; idx < 1024; idx += 256) {
    const int tr = idx >> 6, ky = idx & 63;
    const int row = row0 + tr;        // ((bo*2+dual)*64 + kx)
    const int kx = row & 63;
    const int dual = (row >> 6) & 1;
    const int bo = row >> 7;
    const int b = bo >> 5, o = bo & 31;
    srow[tr][ky] =
        uph(mo[((size_t)((b * 2 + dual) * 32 + o)) * 4096 + kx * 64 + ky]);
  }
  __syncthreads();
  const int n1   = t & 15;
  const int trow = t >> 4;
  float2 a[16];
#pragma unroll
  for (int c = 0; c < 16; ++c) a[c] = make_float2(0.f, 0.f);
  int idx = 0;                       // (kyf*n1) & 255
#pragma unroll
  for (int kyi = 0; kyi < 64; ++kyi) {
    if (kyi == 32) idx = (idx + 192 * n1) & 255;
    cmac(a[kyi & 15], srow[trow][kyi], twc[idx]);
    idx = (idx + n1) & 255;
  }
  const int row = row0 + trow;
  __half2* __restrict__ Tp = T + (size_t)row * 256;
#pragma unroll
  for (int p1 = 0; p1 < 4; ++p1) {
    float2 X[4];
    idft16_p1(a, p1, X);
#pragma unroll
    for (int p2 = 0; p2 < 4; ++p2)
      Tp[n1 + 16 * (p1 + 4 * p2)] = pkh(X[p2].x, X[p2].y);
  }
}

// ---------------------------------------------------------------------------
// I2 (v6): inverse DFT along H, mod-16 classes + idft16; fp16 T in, fp32 out.
// grid 2048 = 128 images * 16 w-tiles(16), block 256.
// ---------------------------------------------------------------------------
__global__ __launch_bounds__(256) void i2_idft_h(const __half2* __restrict__ T,
                                                 float* __restrict__ out) {
  __shared__ float2 twc[256];       // e^{+2pi i t/256}
  __shared__ float2 Tl[2][64][16];
  const int t = threadIdx.x;
  {
    float sv, cv;
    sincosf(TWO_PI * (float)t * (1.0f / 256.0f), &sv, &cv);
    twc[t] = make_float2(cv, sv);
  }
  const int bid = blockIdx.x;
  const int bo = bid >> 4;
  const int w0 = (bid & 15) << 4;
  const __half2* __restrict__ Tp = T + (size_t)bo * 32768;
  for (int idx = t; idx < 2048; idx += 256) {
    const int ww = idx & 15, kxi = (idx >> 4) & 63, dual = idx >> 10;
    Tl[dual][kxi][ww] = uph(Tp[((size_t)dual * 64 + kxi) * 256 + w0 + ww]);
  }
  __syncthreads();
  const int wl = t & 15;
  const int n1 = t >> 4;
  float2 a0[16], a1[16];
#pragma unroll
  for (int c = 0; c < 16; ++c) {
    a0[c] = make_float2(0.f, 0.f);
    a1[c] = make_float2(0.f, 0.f);
  }
  int idx = 0;
#pragma unroll
  for (int kxi = 0; kxi < 64; ++kxi) {
    if (kxi == 32) idx = (idx + 192 * n1) & 255;
    const float2 tv = twc[idx];
    cmac(a0[kxi & 15], Tl[0][kxi][wl], tv);
    cmac(a1[kxi & 15], Tl[1][kxi][wl], tv);
    idx = (idx + n1) & 255;
  }
  const float sc = 1.0f / 65536.0f;
  float4* __restrict__ op = (float4*)out + (size_t)bo * 65536 + w0 + wl;
#pragma unroll
  for (int p1 = 0; p1 < 4; ++p1) {
    float2 X0[4], X1[4];
    idft16_p1(a0, p1, X0);
    idft16_p1(a1, p1, X1);
#pragma unroll
    for (int p2 = 0; p2 < 4; ++p2) {
      const int h = n1 + 16 * (p1 + 4 * p2);
      op[(size_t)h * 256] = make_float4(X0[p2].x * sc, X1[p2].x * sc,
                                        X1[p2].y * sc, X0[p2].y * sc);
    }
  }
}

extern "C" void kernel_launch(void* const* d_in, const int* in_sizes, int n_in,
                              void* d_out, int out_size, void* d_ws, size_t ws_size,
                              hipStream_t stream) {
  const float* x = (const float*)d_in[0];
  const float* wgt = (const float*)d_in[1];
  float* out = (float*)d_out;
  __half2* G  = (__half2*)d_ws;     // 4,194,304 half2 (16.8 MB), reused as T
  __half2* mi = G + 4194304;        // 1,048,576 half2
  __half2* mo = mi + 1048576;       // 1,048,576 half2

  hipLaunchKernelGGL(f1_dft_h, dim3(2048), dim3(256), 0, stream, x, G);
  hipLaunchKernelGGL(f2_dft_w, dim3(1024), dim3(256), 0, stream, G, mi);
  hipLaunchKernelGGL(ein_k,    dim3(512),  dim3(512), 0, stream, mi, wgt, mo);
  hipLaunchKernelGGL(i1_idft_w, dim3(1024), dim3(256), 0, stream, mo, G);
  hipLaunchKernelGGL(i2_idft_h, dim3(2048), dim3(256), 0, stream, G, out);
}

// Round 13
// 124.799 us; speedup vs baseline: 1.1919x; 1.0128x over previous
//
#include <hip/hip_runtime.h>
#include <hip/hip_fp16.h>
#include <math.h>

#define TWO_PI 6.28318530717958647692f

__device__ __forceinline__ void cmac(float2& a, const float2 b, const float2 c) {
  a.x = fmaf(b.x, c.x, fmaf(-b.y, c.y, a.x));
  a.y = fmaf(b.x, c.y, fmaf(b.y, c.x, a.y));
}
__device__ __forceinline__ __half2 pkh(const float xx, const float yy) {
  return __floats2half2_rn(xx, yy);
}
__device__ __forceinline__ float2 uph(const __half2 h) { return __half22float2(h); }

// cos/sin(2*pi*k/16), k=0..15 (positive exponent convention)
#define W16_C {1.f, 0.92387953f, 0.70710678f, 0.38268343f, 0.f, -0.38268343f, -0.70710678f, -0.92387953f, -1.f, -0.92387953f, -0.70710678f, -0.38268343f, 0.f, 0.38268343f, 0.70710678f, 0.92387953f}
#define W16_S {0.f, 0.38268343f, 0.70710678f, 0.92387953f, 1.f, 0.92387953f, 0.70710678f, 0.38268343f, 0.f, -0.38268343f, -0.70710678f, -0.92387953f, -1.f, -0.92387953f, -0.70710678f, -0.38268343f}

// 16-point +exponent DFT bins X[p1+4*p2], p2=0..3, from 16 classes a[c].
__device__ __forceinline__ void idft16_p1(const float2* a, const int p1,
                                          float2* X) {
  const float WC[16] = W16_C;
  const float WS[16] = W16_S;
  float2 tt[4];
#pragma unroll
  for (int r1 = 0; r1 < 4; ++r1) {
    const float2 q0 = a[r1], q1 = a[r1 + 4], q2 = a[r1 + 8], q3 = a[r1 + 12];
    const float2 s = make_float2(q0.x + q2.x, q0.y + q2.y);
    const float2 d = make_float2(q0.x - q2.x, q0.y - q2.y);
    const float2 u = make_float2(q1.x + q3.x, q1.y + q3.y);
    const float2 e = make_float2(q1.x - q3.x, q1.y - q3.y);
    float2 in;
    if (p1 == 0)      in = make_float2(s.x + u.x, s.y + u.y);
    else if (p1 == 1) in = make_float2(d.x - e.y, d.y + e.x);
    else if (p1 == 2) in = make_float2(s.x - u.x, s.y - u.y);
    else              in = make_float2(d.x + e.y, d.y - e.x);
    const float wc = WC[(r1 * p1) & 15], ws = WS[(r1 * p1) & 15];
    tt[r1] = make_float2(fmaf(in.x, wc, -in.y * ws), fmaf(in.y, wc, in.x * ws));
  }
  const float2 s = make_float2(tt[0].x + tt[2].x, tt[0].y + tt[2].y);
  const float2 d = make_float2(tt[0].x - tt[2].x, tt[0].y - tt[2].y);
  const float2 u = make_float2(tt[1].x + tt[3].x, tt[1].y + tt[3].y);
  const float2 e = make_float2(tt[1].x - tt[3].x, tt[1].y - tt[3].y);
  X[0] = make_float2(s.x + u.x, s.y + u.y);
  X[1] = make_float2(d.x - e.y, d.y + e.x);
  X[2] = make_float2(s.x - u.x, s.y - u.y);
  X[3] = make_float2(d.x + e.y, d.y - e.x);
}

// ---------------------------------------------------------------------------
// F1 (v7): pruned DFT along H, mod-16 classes, dual-split 512-thread blocks.
// LDS 36.8KB (pad-17 fp16 tile, repack buffer aliased) -> ~24 waves/CU.
// grid 2048 = 128 img * 16 w-tiles, block 512 = 16 wl x 2 dual x 16 kb.
// ---------------------------------------------------------------------------
__global__ __launch_bounds__(512) void f1_dft_h(const float* __restrict__ x,
                                                __half2* __restrict__ G) {
  __shared__ float2 twn[256];                        // e^{-2pi i t/256}
  __shared__ __align__(16) __half2 yf[64][4][17][2]; // [n1][r][wl(pad17)][dual]
  const int t = threadIdx.x;
  if (t < 256) {
    float sv, cv;
    sincosf(-TWO_PI * (float)t * (1.0f / 256.0f), &sv, &cv);
    twn[t] = make_float2(cv, sv);
  }
  const int bid = blockIdx.x;
  const int img = bid >> 4;            // b*32+c
  const int w0  = (bid & 15) << 4;     // 16-column tile
  const float4* __restrict__ xb = (const float4*)x + (size_t)img * 65536 + w0;
#pragma unroll
  for (int i = 0; i < 2; ++i) {
    const int idxs = t + (i << 9);     // 1024 (n1,wl) slots
    const int n1 = idxs >> 4, wl = idxs & 15;
    const float4 v0 = xb[(size_t)(n1)*256 + wl];
    const float4 v1 = xb[(size_t)(n1 + 64) * 256 + wl];
    const float4 v2 = xb[(size_t)(n1 + 128) * 256 + wl];
    const float4 v3 = xb[(size_t)(n1 + 192) * 256 + wl];
    {  // dual 0: (comp0, comp3)
      const float sx = v0.x + v2.x, sy = v0.w + v2.w;
      const float dx = v0.x - v2.x, dy = v0.w - v2.w;
      const float ux = v1.x + v3.x, uy = v1.w + v3.w;
      const float ex = v1.x - v3.x, ey = v1.w - v3.w;
      yf[n1][0][wl][0] = pkh(sx + ux, sy + uy);
      yf[n1][2][wl][0] = pkh(sx - ux, sy - uy);
      yf[n1][1][wl][0] = pkh(dx + ey, dy - ex);
      yf[n1][3][wl][0] = pkh(dx - ey, dy + ex);
    }
    {  // dual 1: (comp1, comp2)
      const float sx = v0.y + v2.y, sy = v0.z + v2.z;
      const float dx = v0.y - v2.y, dy = v0.z - v2.z;
      const float ux = v1.y + v3.y, uy = v1.z + v3.z;
      const float ex = v1.y - v3.y, ey = v1.z - v3.z;
      yf[n1][0][wl][1] = pkh(sx + ux, sy + uy);
      yf[n1][2][wl][1] = pkh(sx - ux, sy - uy);
      yf[n1][1][wl][1] = pkh(dx + ey, dy - ex);
      yf[n1][3][wl][1] = pkh(dx - ey, dy + ex);
    }
  }
  __syncthreads();
  const int wl   = t & 15;
  const int dual = (t >> 4) & 1;
  const int kb   = t >> 5;             // [0,16)
  const int r    = kb & 3;
  float2 a[16];
#pragma unroll
  for (int c = 0; c < 16; ++c) a[c] = make_float2(0.f, 0.f);
  int idx = 0;                         // (n1*kb) & 255
#pragma unroll
  for (int n1 = 0; n1 < 64; ++n1) {
    const float2 tv = twn[idx];
    const float2 yv = uph(yf[n1][r][wl][dual]);
    cmac(a[n1 & 15], yv, tv);
    idx = (idx + kb) & 255;
  }
  const float WC[16] = W16_C;
  const float WS[16] = W16_S;
  float2 D0 = make_float2(0.f, 0.f), D1 = D0, D2 = D0, D3 = D0;
#pragma unroll
  for (int c = 0; c < 16; ++c) {
    const float2 av = a[c];
    const float cc = WC[c], ss = WS[c];
    const float cc2 = WC[(2 * c) & 15], ss2 = WS[(2 * c) & 15];
    D0.x += av.x;                        D0.y += av.y;
    D1.x = fmaf(av.x, cc,  fmaf( av.y, ss,  D1.x));
    D1.y = fmaf(av.y, cc,  fmaf(-av.x, ss,  D1.y));
    D2.x = fmaf(av.x, cc2, fmaf(-av.y, ss2, D2.x));
    D2.y = fmaf(av.y, cc2, fmaf( av.x, ss2, D2.y));
    D3.x = fmaf(av.x, cc,  fmaf(-av.y, ss,  D3.x));
    D3.y = fmaf(av.y, cc,  fmaf( av.x, ss,  D3.y));
  }
  __syncthreads();  // all yf reads done; safe to overwrite (dl aliases yf)
  __half2(*dl)[64][16] = reinterpret_cast<__half2(*)[64][16]>(&yf[0][0][0][0]);
  dl[dual][kb][wl]      = pkh(D0.x, D0.y);
  dl[dual][kb + 16][wl] = pkh(D1.x, D1.y);
  dl[dual][kb + 32][wl] = pkh(D2.x, D2.y);
  dl[dual][kb + 48][wl] = pkh(D3.x, D3.y);
  __syncthreads();
  const __half2* __restrict__ dfl = &dl[0][0][0];
  const int flat = t << 2;             // 4 half2 per thread (b128)
  const int wq = flat & 15, kx = (flat >> 4) & 63, dd = flat >> 10;
  const size_t row = (size_t)(img * 2 + dd) * 64 + kx;
  *reinterpret_cast<float4*>(&G[row * 256 + w0 + wq]) =
      *reinterpret_cast<const float4*>(&dfl[flat]);
}

// ---------------------------------------------------------------------------
// F2 (v6): pruned DFT along W, mod-16 classes; fp16 G in, fp16 mi out.
// grid 1024 (16 rows/block), block 256 = 16 kslot x 16 trow.
// ---------------------------------------------------------------------------
__global__ __launch_bounds__(256) void f2_dft_w(const __half2* __restrict__ G,
                                                __half2* __restrict__ mi) {
  __shared__ float2 twn[256];
  __shared__ float2 yf[16][65][4];
  const int t = threadIdx.x;
  {
    float sv, cv;
    sincosf(-TWO_PI * (float)t * (1.0f / 256.0f), &sv, &cv);
    twn[t] = make_float2(cv, sv);
  }
  const int row0 = blockIdx.x * 16;
  for (int idx = t; idx < 1024; idx += 256) {
    const int tr = idx >> 6, n1 = idx & 63;
    const __half2* __restrict__ Gp = G + (size_t)(row0 + tr) * 256;
    const float2 z0 = uph(Gp[n1]), z1 = uph(Gp[n1 + 64]);
    const float2 z2 = uph(Gp[n1 + 128]), z3 = uph(Gp[n1 + 192]);
    const float sx = z0.x + z2.x, sy = z0.y + z2.y;
    const float dx = z0.x - z2.x, dy = z0.y - z2.y;
    const float ux = z1.x + z3.x, uy = z1.y + z3.y;
    const float ex = z1.x - z3.x, ey = z1.y - z3.y;
    yf[tr][n1][0] = make_float2(sx + ux, sy + uy);
    yf[tr][n1][2] = make_float2(sx - ux, sy - uy);
    yf[tr][n1][1] = make_float2(dx + ey, dy - ex);
    yf[tr][n1][3] = make_float2(dx - ey, dy + ex);
  }
  __syncthreads();
  const int kslot = t & 15;
  const int trow  = t >> 4;
  const int r     = kslot & 3;
  float2 acc[16];
#pragma unroll
  for (int c = 0; c < 16; ++c) acc[c] = make_float2(0.f, 0.f);
  int idx = 0;
#pragma unroll
  for (int n1 = 0; n1 < 64; ++n1) {
    const float2 tv = twn[idx];
    const float2 yv = yf[trow][n1][r];
    cmac(acc[n1 & 15], yv, tv);
    idx = (idx + kslot) & 255;
  }
  const float WC[16] = W16_C;
  const float WS[16] = W16_S;
  float2 D[4];
  D[0] = make_float2(0.f, 0.f); D[1] = D[0]; D[2] = D[0]; D[3] = D[0];
#pragma unroll
  for (int c = 0; c < 16; ++c) {
    const float2 a = acc[c];
    const float cc = WC[c], ss = WS[c];
    const float cc2 = WC[(2 * c) & 15], ss2 = WS[(2 * c) & 15];
    D[0].x += a.x;                        D[0].y += a.y;
    D[1].x = fmaf(a.x, cc,  fmaf( a.y, ss,  D[1].x));
    D[1].y = fmaf(a.y, cc,  fmaf(-a.x, ss,  D[1].y));
    D[2].x = fmaf(a.x, cc2, fmaf(-a.y, ss2, D[2].x));
    D[2].y = fmaf(a.y, cc2, fmaf( a.x, ss2, D[2].y));
    D[3].x = fmaf(a.x, cc,  fmaf(-a.y, ss,  D[3].x));
    D[3].y = fmaf(a.y, cc,  fmaf( a.x, ss,  D[3].y));
  }
  const int row  = row0 + trow;       // ((img*2+dual)*64 + kx)
  const int kx   = row & 63;
  const int dual = (row >> 6) & 1;
  const int bc   = row >> 7;
  const int b = bc >> 5, cc = bc & 31;
#pragma unroll
  for (int m = 0; m < 4; ++m) {
    const int kyi = kslot + (m << 4);
    mi[((size_t)((b * 2 + dual) * 32 + cc)) * 4096 + kx * 64 + kyi] =
        pkh(D[m].x, D[m].y);
  }
}

// ---------------------------------------------------------------------------
// EIN (v6): Clifford mix; fp16 mi/mo (half2 = (Re,Im) per dual); c-split
// 512-thread blocks (16 waves/CU) + 2-deep weight prefetch; LDS reduce.
// grid 512 = 256 mode-tiles(16) * 2 o-halves.
// ---------------------------------------------------------------------------
__global__ __launch_bounds__(512) void ein_k(const __half2* __restrict__ mi,
                                             const float* __restrict__ wgt,
                                             __half2* __restrict__ mo) {
  __shared__ float si[4][128][16];  // [b][s*32+c][q]  32KB
  const int t = threadIdx.x;
  const int bid = blockIdx.x;
  const int m0 = (bid >> 1) << 4;
  const int oh = bid & 1;
  for (int idx = t; idx < 4096; idx += 512) {
    const int q = idx & 15, c = (idx >> 4) & 31, dual = (idx >> 9) & 1, b = idx >> 10;
    const float2 f = uph(mi[((size_t)((b * 2 + dual) * 32 + c)) * 4096 + m0 + q]);
    if (dual == 0) { si[b][c][q] = f.x;      si[b][96 + c][q] = f.y; }
    else           { si[b][32 + c][q] = f.x; si[b][64 + c][q] = f.y; }
  }
  __syncthreads();
  const int q  = t & 15;
  const int o  = oh * 16 + ((t >> 4) & 15);
  const int ch = t >> 8;             // c-half
  const int c0 = ch << 4;
  const float* __restrict__ wb = wgt + (size_t)o * 131072 + m0 + q;
  float acc[4][4];
#pragma unroll
  for (int b = 0; b < 4; ++b)
#pragma unroll
    for (int r = 0; r < 4; ++r) acc[b][r] = 0.f;
  float wA[4], wB[4];
#pragma unroll
  for (int j = 0; j < 4; ++j) wA[j] = wb[(size_t)j * 4194304 + (size_t)c0 * 4096];
#pragma unroll
  for (int j = 0; j < 4; ++j) wB[j] = wb[(size_t)j * 4194304 + (size_t)(c0 + 1) * 4096];
#pragma unroll 1
  for (int c = c0; c < c0 + 16; ++c) {
    float wv[4];
#pragma unroll
    for (int j = 0; j < 4; ++j) { wv[j] = wA[j]; wA[j] = wB[j]; }
    if (c + 2 < c0 + 16) {
#pragma unroll
      for (int j = 0; j < 4; ++j)
        wB[j] = wb[(size_t)j * 4194304 + (size_t)(c + 2) * 4096];
    }
#pragma unroll
    for (int b = 0; b < 4; ++b) {
      const float iv0 = si[b][c][q];
      const float iv1 = si[b][32 + c][q];
      const float iv2 = si[b][64 + c][q];
      const float iv3 = si[b][96 + c][q];
      acc[b][0] += wv[0] * iv0 + wv[1] * iv1 + wv[2] * iv2 - wv[3] * iv3;
      acc[b][1] += wv[1] * iv0 + wv[0] * iv1 - wv[3] * iv2 + wv[2] * iv3;
      acc[b][2] += wv[2] * iv0 + wv[3] * iv1 + wv[0] * iv2 - wv[1] * iv3;
      acc[b][3] += wv[3] * iv0 + wv[2] * iv1 - wv[1] * iv2 + wv[0] * iv3;
    }
  }
  __syncthreads();                    // si reads done; reuse as reduce buffer
  float* __restrict__ red = &si[0][0][0];   // 256*17 = 4352 floats, fits
  if (ch == 1) {
    const int tt = t & 255;
#pragma unroll
    for (int b = 0; b < 4; ++b)
#pragma unroll
      for (int r = 0; r < 4; ++r) red[tt * 17 + b * 4 + r] = acc[b][r];
  }
  __syncthreads();
  if (ch == 0) {
#pragma unroll
    for (int b = 0; b < 4; ++b)
#pragma unroll
      for (int r = 0; r < 4; ++r) acc[b][r] += red[t * 17 + b * 4 + r];
#pragma unroll
    for (int b = 0; b < 4; ++b) {
      mo[((size_t)((b * 2 + 0) * 32 + o)) * 4096 + m0 + q] = pkh(acc[b][0], acc[b][3]);
      mo[((size_t)((b * 2 + 1) * 32 + o)) * 4096 + m0 + q] = pkh(acc[b][1], acc[b][2]);
    }
  }
}

// ---------------------------------------------------------------------------
// I1 (v6): inverse DFT along W, mod-16 classes + idft16; fp16 mo in, fp16 T out.
// grid 1024 (16 rows/block), block 256 = 16 n1 x 16 trow.
// ---------------------------------------------------------------------------
__global__ __launch_bounds__(256) void i1_idft_w(const __half2* __restrict__ mo,
                                                 __half2* __restrict__ T) {
  __shared__ float2 twc[256];       // e^{+2pi i t/256}
  __shared__ float2 srow[16][66];
  const int t = threadIdx.x;
  {
    float sv, cv;
    sincosf(TWO_PI * (float)t * (1.0f / 256.0f), &sv, &cv);
    twc[t] = make_float2(cv, sv);
  }
  const int row0 = blockIdx.x * 16;
  for (int idx = t; idx < 1024; idx += 256) {
    const int tr = idx >> 6, ky = idx & 63;
    const int row = row0 + tr;        // ((bo*2+dual)*64 + kx)
    const int kx = row & 63;
    const int dual = (row >> 6) & 1;
    const int bo = row >> 7;
    const int b = bo >> 5, o = bo & 31;
    srow[tr][ky] =
        uph(mo[((size_t)((b * 2 + dual) * 32 + o)) * 4096 + kx * 64 + ky]);
  }
  __syncthreads();
  const int n1   = t & 15;
  const int trow = t >> 4;
  float2 a[16];
#pragma unroll
  for (int c = 0; c < 16; ++c) a[c] = make_float2(0.f, 0.f);
  int idx = 0;                       // (kyf*n1) & 255
#pragma unroll
  for (int kyi = 0; kyi < 64; ++kyi) {
    if (kyi == 32) idx = (idx + 192 * n1) & 255;
    cmac(a[kyi & 15], srow[trow][kyi], twc[idx]);
    idx = (idx + n1) & 255;
  }
  const int row = row0 + trow;
  __half2* __restrict__ Tp = T + (size_t)row * 256;
#pragma unroll
  for (int p1 = 0; p1 < 4; ++p1) {
    float2 X[4];
    idft16_p1(a, p1, X);
#pragma unroll
    for (int p2 = 0; p2 < 4; ++p2)
      Tp[n1 + 16 * (p1 + 4 * p2)] = pkh(X[p2].x, X[p2].y);
  }
}

// ---------------------------------------------------------------------------
// I2 (v6): inverse DFT along H, mod-16 classes + idft16; fp16 T in, fp32 out.
// grid 2048 = 128 images * 16 w-tiles(16), block 256.
// ---------------------------------------------------------------------------
__global__ __launch_bounds__(256) void i2_idft_h(const __half2* __restrict__ T,
                                                 float* __restrict__ out) {
  __shared__ float2 twc[256];       // e^{+2pi i t/256}
  __shared__ float2 Tl[2][64][16];
  const int t = threadIdx.x;
  {
    float sv, cv;
    sincosf(TWO_PI * (float)t * (1.0f / 256.0f), &sv, &cv);
    twc[t] = make_float2(cv, sv);
  }
  const int bid = blockIdx.x;
  const int bo = bid >> 4;
  const int w0 = (bid & 15) << 4;
  const __half2* __restrict__ Tp = T + (size_t)bo * 32768;
  for (int idx = t; idx < 2048; idx += 256) {
    const int ww = idx & 15, kxi = (idx >> 4) & 63, dual = idx >> 10;
    Tl[dual][kxi][ww] = uph(Tp[((size_t)dual * 64 + kxi) * 256 + w0 + ww]);
  }
  __syncthreads();
  const int wl = t & 15;
  const int n1 = t >> 4;
  float2 a0[16], a1[16];
#pragma unroll
  for (int c = 0; c < 16; ++c) {
    a0[c] = make_float2(0.f, 0.f);
    a1[c] = make_float2(0.f, 0.f);
  }
  int idx = 0;
#pragma unroll
  for (int kxi = 0; kxi < 64; ++kxi) {
    if (kxi == 32) idx = (idx + 192 * n1) & 255;
    const float2 tv = twc[idx];
    cmac(a0[kxi & 15], Tl[0][kxi][wl], tv);
    cmac(a1[kxi & 15], Tl[1][kxi][wl], tv);
    idx = (idx + n1) & 255;
  }
  const float sc = 1.0f / 65536.0f;
  float4* __restrict__ op = (float4*)out + (size_t)bo * 65536 + w0 + wl;
#pragma unroll
  for (int p1 = 0; p1 < 4; ++p1) {
    float2 X0[4], X1[4];
    idft16_p1(a0, p1, X0);
    idft16_p1(a1, p1, X1);
#pragma unroll
    for (int p2 = 0; p2 < 4; ++p2) {
      const int h = n1 + 16 * (p1 + 4 * p2);
      op[(size_t)h * 256] = make_float4(X0[p2].x * sc, X1[p2].x * sc,
                                        X1[p2].y * sc, X0[p2].y * sc);
    }
  }
}

extern "C" void kernel_launch(void* const* d_in, const int* in_sizes, int n_in,
                              void* d_out, int out_size, void* d_ws, size_t ws_size,
                              hipStream_t stream) {
  const float* x = (const float*)d_in[0];
  const float* wgt = (const float*)d_in[1];
  float* out = (float*)d_out;
  __half2* G  = (__half2*)d_ws;     // 4,194,304 half2 (16.8 MB), reused as T
  __half2* mi = G + 4194304;        // 1,048,576 half2
  __half2* mo = mi + 1048576;       // 1,048,576 half2

  hipLaunchKernelGGL(f1_dft_h, dim3(2048), dim3(512), 0, stream, x, G);
  hipLaunchKernelGGL(f2_dft_w, dim3(1024), dim3(256), 0, stream, G, mi);
  hipLaunchKernelGGL(ein_k,    dim3(512),  dim3(512), 0, stream, mi, wgt, mo);
  hipLaunchKernelGGL(i1_idft_w, dim3(1024), dim3(256), 0, stream, mo, G);
  hipLaunchKernelGGL(i2_idft_h, dim3(2048), dim3(256), 0, stream, G, out);
}